// Round 1
// baseline (206.402 us; speedup 1.0000x reference)
//
#include <hip/hip_runtime.h>

#define B_  32
#define C_  256
#define H_  56
#define W_  56
#define HW  3136      // H_*W_
#define KK  9
#define NPLANES (B_*C_)   // 8192
#define NP  8             // planes per dconv block (all within one batch: 8 | 256)
#define DGRID (NPLANES/NP) // 1024 blocks -> exactly 4 blocks/CU on 256 CUs

typedef float v4f __attribute__((ext_vector_type(4)));

// ---------------------------------------------------------------------------
// Kernel 1: global average pool. One WAVE per (b,c) plane, 4 planes/block.
// Pure shuffle reduction; regular loads keep x resident in L3 for dconv.
// Already at the read-BW floor (~16 us) — unchanged.
// ---------------------------------------------------------------------------
__global__ __launch_bounds__(256) void pool_kernel(const float* __restrict__ x,
                                                   float* __restrict__ pooled) {
    const int wid  = threadIdx.x >> 6;
    const int lane = threadIdx.x & 63;
    const int plane = blockIdx.x * 4 + wid;             // 2048 blocks * 4 waves
    const float4* xp = (const float4*)(x + (size_t)plane * HW);

    float s = 0.f;
    #pragma unroll
    for (int k = 0; k < 12; ++k) {                      // 12*64 = 768 strips
        float4 v = xp[lane + k * 64];
        s += (v.x + v.y) + (v.z + v.w);
    }
    if (lane < 16) {                                    // remainder 768..783
        float4 v = xp[768 + lane];
        s += (v.x + v.y) + (v.z + v.w);
    }
    #pragma unroll
    for (int off = 32; off > 0; off >>= 1)
        s += __shfl_down(s, off, 64);
    if (lane == 0)
        pooled[plane] = s * (1.0f / (float)HW);
}

// ---------------------------------------------------------------------------
// Kernel-generation for one plane: 9 taps, 16 lanes/tap, 16-ch partials,
// shuffle-reduced. Runs on threads 0..143 while next plane's x loads are in
// flight. Writes into the double-buffered wsh slot.
// ---------------------------------------------------------------------------
__device__ __forceinline__ void kerngen(int t, int plane,
                                        const float* __restrict__ pooled,
                                        const float* __restrict__ Wk,
                                        const float* __restrict__ bk,
                                        float* __restrict__ wdst) {
    if (t < 144) {
        const int b  = plane >> 8;
        const int c  = plane & 255;
        const int o  = t >> 4;                          // 0..8
        const int ch = (t & 15) << 4;                   // 0,16,...,240
        const int og = c * KK + o;                      // global output row
        const float4* wr = (const float4*)(Wk + (size_t)og * C_ + ch);
        const float4* pr = (const float4*)(pooled + b * C_ + ch);
        float s = 0.f;
        #pragma unroll
        for (int i = 0; i < 4; ++i) {
            float4 w = wr[i];
            float4 p = pr[i];
            s += w.x * p.x + w.y * p.y + w.z * p.z + w.w * p.w;
        }
        #pragma unroll
        for (int off = 8; off > 0; off >>= 1)           // reduce 16-lane groups
            s += __shfl_down(s, off, 16);
        if ((t & 15) == 0)
            wdst[o] = fmaxf(s + bk[og], 0.f);
    }
}

// Write the staged registers into the 58x58 zero-padded interior.
__device__ __forceinline__ void stage_write(float* __restrict__ dst, int t,
                                            float4 v0, float4 v1, float4 v2, float4 v3) {
    int s, r, c0, base;
    s = t;        r = s / 14; c0 = (s % 14) * 4; base = (r + 1) * 58 + c0 + 1;
    dst[base] = v0.x; dst[base + 1] = v0.y; dst[base + 2] = v0.z; dst[base + 3] = v0.w;
    s = t + 256;  r = s / 14; c0 = (s % 14) * 4; base = (r + 1) * 58 + c0 + 1;
    dst[base] = v1.x; dst[base + 1] = v1.y; dst[base + 2] = v1.z; dst[base + 3] = v1.w;
    s = t + 512;  r = s / 14; c0 = (s % 14) * 4; base = (r + 1) * 58 + c0 + 1;
    dst[base] = v2.x; dst[base + 1] = v2.y; dst[base + 2] = v2.z; dst[base + 3] = v2.w;
    if (t < 16) {
        s = t + 768; r = s / 14; c0 = (s % 14) * 4; base = (r + 1) * 58 + c0 + 1;
        dst[base] = v3.x; dst[base + 1] = v3.y; dst[base + 2] = v3.z; dst[base + 3] = v3.w;
    }
}

// ---------------------------------------------------------------------------
// Kernel 2 (pipelined): NP=8 planes per block, double-buffered input tile.
// Per plane p:
//   A: issue plane p+1 global loads (stay in flight under B+C)
//   B: kern-gen p+1 -> wsh[nxt]
//   C: compute plane p from buf[cur] -> linear LDS out-stage
//   D: barrier
//   E: copy out-stage -> out with fully 64B-aligned NT dwordx4 (no partial lines)
//   F: ds_write staged regs -> buf[nxt]   (vmcnt wait lands ~2000 cyc after issue)
//   G: barrier
// LDS = 2*13456 + 12544 + 128 = 39.6 KB -> 4 blocks/CU (grid is exactly 4/CU).
// ---------------------------------------------------------------------------
__global__ __launch_bounds__(256, 4) void dconv_kernel(const float* __restrict__ x,
                                                       const float* __restrict__ pooled,
                                                       const float* __restrict__ Wk,
                                                       const float* __restrict__ bk,
                                                       float* __restrict__ out) {
    __shared__ float buf[2][58 * 58];
    __shared__ float ost[56 * 56];
    __shared__ float wsh[2][16];

    const int t  = threadIdx.x;
    const int p0 = blockIdx.x * NP;                     // first plane; all NP share batch

    // Zero halos of both buffers once (interior writes never touch them).
    #pragma unroll
    for (int q = 0; q < 2; ++q) {
        if (t < 58) { buf[q][t] = 0.f; buf[q][57 * 58 + t] = 0.f; }
        if (t < 56) { buf[q][(t + 1) * 58] = 0.f; buf[q][(t + 1) * 58 + 57] = 0.f; }
    }

    // Prologue: stage plane p0.
    float4 s0, s1, s2, s3 = make_float4(0.f, 0.f, 0.f, 0.f);
    {
        const float4* xp = (const float4*)(x + (size_t)p0 * HW);
        s0 = xp[t]; s1 = xp[t + 256]; s2 = xp[t + 512];
        if (t < 16) s3 = xp[t + 768];
    }
    kerngen(t, p0, pooled, Wk, bk, wsh[0]);
    stage_write(buf[0], t, s0, s1, s2, s3);
    __syncthreads();

    for (int p = 0; p < NP; ++p) {
        const int cur = p & 1, nxt = cur ^ 1;
        const bool more = (p + 1 < NP);

        // A+B: prefetch next plane + generate its taps while loads fly.
        if (more) {
            const float4* xp = (const float4*)(x + (size_t)(p0 + p + 1) * HW);
            s0 = xp[t]; s1 = xp[t + 256]; s2 = xp[t + 512];
            if (t < 16) s3 = xp[t + 768];
            kerngen(t, p0 + p + 1, pooled, Wk, bk, wsh[nxt]);
        }

        // C: compute plane p -> LDS out-stage (16B-aligned ds_write_b128).
        {
            const float* wc = wsh[cur];
            const float w0 = wc[0], w1 = wc[1], w2 = wc[2],
                        w3 = wc[3], w4 = wc[4], w5 = wc[5],
                        w6 = wc[6], w7 = wc[7], w8 = wc[8];
            const float* bs = buf[cur];
            for (int i = t; i < 392; i += 256) {
                const int rp = i / 14;                  // out rows 2rp, 2rp+1
                const int c0 = (i % 14) * 4;            // 0,4,...,52
                const float* R0 = &bs[(2 * rp + 0) * 58 + c0];
                const float* R1 = &bs[(2 * rp + 1) * 58 + c0];
                const float* R2 = &bs[(2 * rp + 2) * 58 + c0];
                const float* R3 = &bs[(2 * rp + 3) * 58 + c0];
                float2 p0v = *(const float2*)(R0), p1v = *(const float2*)(R0 + 2), p2v = *(const float2*)(R0 + 4);
                float2 q0v = *(const float2*)(R1), q1v = *(const float2*)(R1 + 2), q2v = *(const float2*)(R1 + 4);
                float2 r0v = *(const float2*)(R2), r1v = *(const float2*)(R2 + 2), r2v = *(const float2*)(R2 + 4);
                float2 u0v = *(const float2*)(R3), u1v = *(const float2*)(R3 + 2), u2v = *(const float2*)(R3 + 4);
                const float a0 = p0v.x, a1 = p0v.y, a2 = p1v.x, a3 = p1v.y, a4 = p2v.x, a5 = p2v.y;
                const float b0 = q0v.x, b1 = q0v.y, b2 = q1v.x, b3 = q1v.y, b4 = q2v.x, b5 = q2v.y;
                const float e0 = r0v.x, e1 = r0v.y, e2 = r1v.x, e3 = r1v.y, e4 = r2v.x, e5 = r2v.y;
                const float d0 = u0v.x, d1 = u0v.y, d2 = u1v.x, d3 = u1v.y, d4 = u2v.x, d5 = u2v.y;

                v4f t0, t1;
                t0.x = a0*w0 + a1*w1 + a2*w2 + b0*w3 + b1*w4 + b2*w5 + e0*w6 + e1*w7 + e2*w8;
                t0.y = a1*w0 + a2*w1 + a3*w2 + b1*w3 + b2*w4 + b3*w5 + e1*w6 + e2*w7 + e3*w8;
                t0.z = a2*w0 + a3*w1 + a4*w2 + b2*w3 + b3*w4 + b4*w5 + e2*w6 + e3*w7 + e4*w8;
                t0.w = a3*w0 + a4*w1 + a5*w2 + b3*w3 + b4*w4 + b5*w5 + e3*w6 + e4*w7 + e5*w8;
                t1.x = b0*w0 + b1*w1 + b2*w2 + e0*w3 + e1*w4 + e2*w5 + d0*w6 + d1*w7 + d2*w8;
                t1.y = b1*w0 + b2*w1 + b3*w2 + e1*w3 + e2*w4 + e3*w5 + d1*w6 + d2*w7 + d3*w8;
                t1.z = b2*w0 + b3*w1 + b4*w2 + e2*w3 + e3*w4 + e4*w5 + d2*w6 + d3*w7 + d4*w8;
                t1.w = b3*w0 + b4*w1 + b5*w2 + e3*w3 + e4*w4 + e5*w5 + d3*w6 + d4*w7 + d5*w8;

                *(v4f*)&ost[(2 * rp + 0) * 56 + c0] = t0;   // 16B-aligned LDS writes
                *(v4f*)&ost[(2 * rp + 1) * 56 + c0] = t1;
            }
        }
        __syncthreads();                                 // D: ost complete

        // E: linear copy-out — every NT dwordx4 wave-span is 1024B, 64B-aligned.
        {
            float* op = out + (size_t)(p0 + p) * HW;
            const v4f* os = (const v4f*)ost;
            __builtin_nontemporal_store(os[t],       (v4f*)op + t);
            __builtin_nontemporal_store(os[t + 256], (v4f*)op + t + 256);
            __builtin_nontemporal_store(os[t + 512], (v4f*)op + t + 512);
            if (t < 16)
                __builtin_nontemporal_store(os[t + 768], (v4f*)op + t + 768);
        }

        // F: land the prefetched plane into the other buffer.
        if (more)
            stage_write(buf[nxt], t, s0, s1, s2, s3);
        __syncthreads();                                 // G: buf[nxt]+wsh[nxt] ready, ost free
    }
}

extern "C" void kernel_launch(void* const* d_in, const int* in_sizes, int n_in,
                              void* d_out, int out_size, void* d_ws, size_t ws_size,
                              hipStream_t stream) {
    const float* x  = (const float*)d_in[0];   // [B,C,H,W]
    const float* Wk = (const float*)d_in[1];   // [C*K*K, C]
    const float* bk = (const float*)d_in[2];   // [C*K*K]
    float* out = (float*)d_out;                // [B,C,H,W]

    float* pooled = (float*)d_ws;              // B*C = 8192 floats

    pool_kernel<<<NPLANES / 4, 256, 0, stream>>>(x, pooled);
    dconv_kernel<<<DGRID, 256, 0, stream>>>(x, pooled, Wk, bk, out);
}